// Round 5
// baseline (140.788 us; speedup 1.0000x reference)
//
#include <hip/hip_runtime.h>
#include <hip/hip_bf16.h>

typedef unsigned short u16;
typedef unsigned int u32;

#define THREADS 256
constexpr int CH = 64;        // in/out channels
constexpr int PP = 32;        // neighbors per point
constexpr int TM = 16;        // points per block

// ---- LDS layout (bytes) ----
// W:  [16 m][16 g][32 p] bf16, A-fragment order = 16384
// Mb: [8 pt][1024 k] bf16, XOR-swizzled (byte ^= ((mloc&7)^(g&7))<<4) = 16384
constexpr int W_OFF  = 0;
constexpr int MB_OFF = 16384;
constexpr int LDS_BYTES = 32768;   // 5 blocks/CU at 160 KiB

typedef __attribute__((ext_vector_type(8))) short short8;
typedef __attribute__((ext_vector_type(4))) float f32x4;

static __device__ __forceinline__ u16 f2bf_rne(float f) {
  __hip_bfloat16 h = __float2bfloat16(f);
  return __builtin_bit_cast(u16, h);
}
static __device__ __forceinline__ u16 rbf(float f) {  // cheap round-half-up (2 VALU)
  u32 u = __builtin_bit_cast(u32, f);
  return (u16)((u + 0x8000u) >> 16);
}

// ---- prep 1: features f32 -> bf16 ----
__global__ void prep_feat(const float* __restrict__ in, u16* __restrict__ outb, int n2) {
  int i = blockIdx.x * blockDim.x + threadIdx.x;
  if (i < n2) {
    float2 v = ((const float2*)in)[i];
    u32 u = (u32)f2bf_rne(v.x) | ((u32)f2bf_rne(v.y) << 16);
    ((u32*)outb)[i] = u;
  }
}

// ---- prep 2: kernel f32 [g][i][o] -> bf16 in B-fragment order ----
__global__ void prep_k2f(const float* __restrict__ kern, u16* __restrict__ k2f) {
  int d = blockIdx.x * blockDim.x + threadIdx.x;   // 65536 total
  int e = d & 7, l = (d >> 3) & 63, ot = (d >> 9) & 3, ks = d >> 11;
  int k = ks * 32 + (l >> 4) * 8 + e;
  int o = ot * 16 + (l & 15);
  k2f[d] = f2bf_rne(kern[k * 64 + o]);
}

// ---- main fused kernel: 16 points per block, 4 waves, 5 blocks/CU ----
__global__ __launch_bounds__(THREADS, 5) void cconv_main(
    const int* __restrict__ recv, const float* __restrict__ relpos,
    const float* __restrict__ wsup, const int* __restrict__ aptr,
    const u16* __restrict__ fbf, const u16* __restrict__ k2f,
    const float* __restrict__ bias, float* __restrict__ out) {
  __shared__ __align__(16) char smem[LDS_BYTES];
  const int tid = threadIdx.x;
  const int n0 = blockIdx.x * TM;
  const int wid = tid >> 6, lane = tid & 63;
  const int l15 = lane & 15, l4 = lane >> 4;

  // ---- P0: full W -> LDS in A-fragment order [m][g][p], r2's per-edge scalar idiom ----
  {
    const float invws = 1.0f / wsup[0];
    int a = aptr[0];
    if (a < 0 || a > 64) a = (int)(*(const float*)aptr);  // dtype fallback
    #pragma unroll
    for (int ee = 0; ee < 2; ++ee) {
      const int e = tid + ee * 256;
      const int m = e >> 5, p = e & 31;
      const int ei = (n0 + m) * PP + p;
      const float2 rp2 = ((const float2*)relpos)[ei];
      const float rx = rp2.x * invws, ry = rp2.y * invws;
      const float d2 = rx * rx + ry * ry;
      const float w1 = fmaxf(1.0f - d2, 0.0f);
      float win = 1.0f;
      for (int q = 0; q < a; ++q) win *= w1;
      float gy = fminf(fmaxf((rx + 1.0f) * 1.5f, 0.0f), 3.0f);
      float gx = fminf(fmaxf((ry + 1.0f) * 1.5f, 0.0f), 3.0f);
      int y0 = (int)gy; y0 = y0 > 2 ? 2 : y0;
      int x0 = (int)gx; x0 = x0 > 2 ? 2 : x0;
      const float fy = gy - (float)y0, fx = gx - (float)x0;
      u16* wp = (u16*)(smem + W_OFF) + m * 512 + p;   // elem [m][g][p] = m*512 + g*32 + p
      #pragma unroll
      for (int g = 0; g < 16; ++g) {
        const int y = g >> 2, x = g & 3;
        const float wyv = (y == y0) ? (1.0f - fy) : (y == y0 + 1) ? fy : 0.0f;
        const float wxv = (x == x0) ? (1.0f - fx) : (x == x0 + 1) ? fx : 0.0f;
        wp[g * 32] = rbf(win * wyv * wxv);
      }
    }
  }
  __syncthreads();

  f32x4 accA = {0.f, 0.f, 0.f, 0.f}, accB = {0.f, 0.f, 0.f, 0.f};

  // ================= h = 0: points 0..7 =================
  #pragma unroll
  for (int t = 0; t < 2; ++t) {
    const int mloc = wid * 2 + t;
    const int m = mloc;            // h=0
    const int* rp = recv + (n0 + m) * PP + l4 * 8;
    const int4 A4 = *(const int4*)rp;
    const int4 B4 = *(const int4*)(rp + 4);
    const short8 af = *(const short8*)(smem + W_OFF + m * 1024 + l15 * 64 + l4 * 16);
    u32 vo[8];
    vo[0] = (u32)A4.x * 64u + (u32)l15; vo[1] = (u32)A4.y * 64u + (u32)l15;
    vo[2] = (u32)A4.z * 64u + (u32)l15; vo[3] = (u32)A4.w * 64u + (u32)l15;
    vo[4] = (u32)B4.x * 64u + (u32)l15; vo[5] = (u32)B4.y * 64u + (u32)l15;
    vo[6] = (u32)B4.z * 64u + (u32)l15; vo[7] = (u32)B4.w * 64u + (u32)l15;
    f32x4 accm[4];
    #pragma unroll
    for (int ib = 0; ib < 4; ++ib) {
      u32 q[8];
      #pragma unroll
      for (int e = 0; e < 8; ++e) q[e] = (u32)fbf[vo[e] + ib * 16];
      union { u32 u[4]; short8 s; } bb;
      #pragma unroll
      for (int j = 0; j < 4; ++j) bb.u[j] = q[2 * j] | (q[2 * j + 1] << 16);
      const f32x4 cz = {0.f, 0.f, 0.f, 0.f};
      accm[ib] = __builtin_amdgcn_mfma_f32_16x16x32_bf16(af, bb.s, cz, 0, 0, 0);
    }
    #pragma unroll
    for (int ib = 0; ib < 4; ++ib)
      #pragma unroll
      for (int r = 0; r < 4; ++r) {
        const int g = l4 * 4 + r;
        const u32 k = (u32)(g * 64 + ib * 16 + l15);
        u32 byt = (u32)mloc * 2048u + k * 2u;
        byt ^= ((u32)((mloc & 7) ^ (g & 7)) << 4);
        *(u16*)(smem + MB_OFF + byt) = rbf(accm[ib][r]);
      }
  }
  __syncthreads();
  {
    const u32 rowb = (u32)(l15 & 7) * 2048u;
    const u32 swl = (u32)(l15 & 7) << 4;
    #pragma unroll
    for (int ks = 0; ks < 32; ++ks) {
      const u32 kc = (u32)ks * 32u + (u32)l4 * 8u;
      const u32 g7 = (((kc >> 6) & 7u) << 4);
      const u32 byt = (rowb + kc * 2u) ^ swl ^ g7;
      const short8 a2 = *(const short8*)(smem + MB_OFF + byt);
      const short8 b2 = *(const short8*)(k2f + ((u32)(ks * 4 + wid) * 64u + (u32)lane) * 8u);
      accA = __builtin_amdgcn_mfma_f32_16x16x32_bf16(a2, b2, accA, 0, 0, 0);
    }
  }
  __syncthreads();

  // ================= h = 1: points 8..15 =================
  #pragma unroll
  for (int t = 0; t < 2; ++t) {
    const int mloc = wid * 2 + t;
    const int m = 8 + mloc;        // h=1
    const int* rp = recv + (n0 + m) * PP + l4 * 8;
    const int4 A4 = *(const int4*)rp;
    const int4 B4 = *(const int4*)(rp + 4);
    const short8 af = *(const short8*)(smem + W_OFF + m * 1024 + l15 * 64 + l4 * 16);
    u32 vo[8];
    vo[0] = (u32)A4.x * 64u + (u32)l15; vo[1] = (u32)A4.y * 64u + (u32)l15;
    vo[2] = (u32)A4.z * 64u + (u32)l15; vo[3] = (u32)A4.w * 64u + (u32)l15;
    vo[4] = (u32)B4.x * 64u + (u32)l15; vo[5] = (u32)B4.y * 64u + (u32)l15;
    vo[6] = (u32)B4.z * 64u + (u32)l15; vo[7] = (u32)B4.w * 64u + (u32)l15;
    f32x4 accm[4];
    #pragma unroll
    for (int ib = 0; ib < 4; ++ib) {
      u32 q[8];
      #pragma unroll
      for (int e = 0; e < 8; ++e) q[e] = (u32)fbf[vo[e] + ib * 16];
      union { u32 u[4]; short8 s; } bb;
      #pragma unroll
      for (int j = 0; j < 4; ++j) bb.u[j] = q[2 * j] | (q[2 * j + 1] << 16);
      const f32x4 cz = {0.f, 0.f, 0.f, 0.f};
      accm[ib] = __builtin_amdgcn_mfma_f32_16x16x32_bf16(af, bb.s, cz, 0, 0, 0);
    }
    #pragma unroll
    for (int ib = 0; ib < 4; ++ib)
      #pragma unroll
      for (int r = 0; r < 4; ++r) {
        const int g = l4 * 4 + r;
        const u32 k = (u32)(g * 64 + ib * 16 + l15);
        u32 byt = (u32)mloc * 2048u + k * 2u;
        byt ^= ((u32)((mloc & 7) ^ (g & 7)) << 4);
        *(u16*)(smem + MB_OFF + byt) = rbf(accm[ib][r]);
      }
  }
  __syncthreads();
  {
    const u32 rowb = (u32)(l15 & 7) * 2048u;
    const u32 swl = (u32)(l15 & 7) << 4;
    #pragma unroll
    for (int ks = 0; ks < 32; ++ks) {
      const u32 kc = (u32)ks * 32u + (u32)l4 * 8u;
      const u32 g7 = (((kc >> 6) & 7u) << 4);
      const u32 byt = (rowb + kc * 2u) ^ swl ^ g7;
      const short8 a2 = *(const short8*)(smem + MB_OFF + byt);
      const short8 b2 = *(const short8*)(k2f + ((u32)(ks * 4 + wid) * 64u + (u32)lane) * 8u);
      accB = __builtin_amdgcn_mfma_f32_16x16x32_bf16(a2, b2, accB, 0, 0, 0);
    }
  }

  // ---- epilogue: rows n = l4*4 + r; l4<2 -> points 0-7 (accA), l4>=2 -> 8-15 (accB)
  const int o = wid * 16 + l15;
  const float bv = bias[o];
  const f32x4 accw = (l4 < 2) ? accA : accB;
  #pragma unroll
  for (int r = 0; r < 4; ++r)
    out[(n0 + l4 * 4 + r) * CH + o] = accw[r] * (1.0f / 32.0f) + bv;
}

extern "C" void kernel_launch(void* const* d_in, const int* in_sizes, int n_in,
                              void* d_out, int out_size, void* d_ws, size_t ws_size,
                              hipStream_t stream) {
  const float* features = (const float*)d_in[0];
  const int* receivers  = (const int*)d_in[1];
  const float* relpos   = (const float*)d_in[2];
  const float* wsup     = (const float*)d_in[3];
  const int* aptr       = (const int*)d_in[4];
  const float* kern     = (const float*)d_in[5];
  const float* bias     = (const float*)d_in[6];
  float* out = (float*)d_out;

  const int N = in_sizes[0] / CH;   // 50000
  u16* fbf = (u16*)d_ws;                                    // N*64 bf16 = 6.4 MB
  u16* k2f = (u16*)((char*)d_ws + (size_t)N * CH * 2);      // 128 KB, frag-ordered

  const int nfeat2 = in_sizes[0] / 2;
  prep_feat<<<dim3((nfeat2 + 255) / 256), dim3(256), 0, stream>>>(features, fbf, nfeat2);
  prep_k2f<<<dim3(65536 / 256), dim3(256), 0, stream>>>(kern, k2f);

  cconv_main<<<dim3(N / TM), dim3(THREADS), 0, stream>>>(
      receivers, relpos, wsup, aptr, fbf, k2f, bias, out);
}

// Round 6
// 81.532 us; speedup vs baseline: 1.7268x; 1.7268x over previous
//
#include <hip/hip_runtime.h>
#include <hip/hip_bf16.h>

typedef unsigned short u16;
typedef unsigned int u32;

#define THREADS 256
constexpr int CH = 64;        // in/out channels
constexpr int PP = 32;        // neighbors per point
constexpr int TM = 16;        // points per block

// ---- LDS layout (bytes) ----
// W:  [16 m][16 g][32 p] bf16, A-fragment order = 16384
// Mb: [8 pt][1024 k] bf16, XOR-swizzled (byte ^= ((mloc&7)^(g&7))<<4) = 16384
constexpr int W_OFF  = 0;
constexpr int MB_OFF = 16384;
constexpr int LDS_BYTES = 32768;   // 5 blocks/CU at 160 KiB

typedef __attribute__((ext_vector_type(8))) short short8;
typedef __attribute__((ext_vector_type(4))) float f32x4;

static __device__ __forceinline__ u16 f2bf_rne(float f) {
  __hip_bfloat16 h = __float2bfloat16(f);
  return __builtin_bit_cast(u16, h);
}
static __device__ __forceinline__ u16 rbf(float f) {  // cheap round-half-up (2 VALU)
  u32 u = __builtin_bit_cast(u32, f);
  return (u16)((u + 0x8000u) >> 16);
}

// ---- prep 1: features f32 -> bf16 ----
__global__ void prep_feat(const float* __restrict__ in, u16* __restrict__ outb, int n2) {
  int i = blockIdx.x * blockDim.x + threadIdx.x;
  if (i < n2) {
    float2 v = ((const float2*)in)[i];
    u32 u = (u32)f2bf_rne(v.x) | ((u32)f2bf_rne(v.y) << 16);
    ((u32*)outb)[i] = u;
  }
}

// ---- prep 2: kernel f32 [g][i][o] -> bf16 in B-fragment order ----
__global__ void prep_k2f(const float* __restrict__ kern, u16* __restrict__ k2f) {
  int d = blockIdx.x * blockDim.x + threadIdx.x;   // 65536 total
  int e = d & 7, l = (d >> 3) & 63, ot = (d >> 9) & 3, ks = d >> 11;
  int k = ks * 32 + (l >> 4) * 8 + e;
  int o = ot * 16 + (l & 15);
  k2f[d] = f2bf_rne(kern[k * 64 + o]);
}

// ---- main fused kernel: 16 points per block, 4 waves, 5 blocks/CU ----
__global__ __launch_bounds__(THREADS, 5) void cconv_main(
    const int* __restrict__ recv, const float* __restrict__ relpos,
    const float* __restrict__ wsup, const int* __restrict__ aptr,
    const u16* __restrict__ fbf, const u16* __restrict__ k2f,
    const float* __restrict__ bias, float* __restrict__ out) {
  __shared__ __align__(16) char smem[LDS_BYTES];
  const int tid = threadIdx.x;
  const int n0 = blockIdx.x * TM;
  const int wid = tid >> 6, lane = tid & 63;
  const int l15 = lane & 15, l4 = lane >> 4;

  // ---- P0: full W -> LDS in A-fragment order [m][g][p] ----
  {
    const float invws = 1.0f / wsup[0];
    int a = aptr[0];
    if (a < 0 || a > 64) a = (int)(*(const float*)aptr);  // dtype fallback
    #pragma unroll
    for (int ee = 0; ee < 2; ++ee) {
      const int e = tid + ee * 256;
      const int m = e >> 5, p = e & 31;
      const int ei = (n0 + m) * PP + p;
      const float2 rp2 = ((const float2*)relpos)[ei];
      const float rx = rp2.x * invws, ry = rp2.y * invws;
      const float d2 = rx * rx + ry * ry;
      const float w1 = fmaxf(1.0f - d2, 0.0f);
      float win = 1.0f;
      for (int q = 0; q < a; ++q) win *= w1;
      float gy = fminf(fmaxf((rx + 1.0f) * 1.5f, 0.0f), 3.0f);
      float gx = fminf(fmaxf((ry + 1.0f) * 1.5f, 0.0f), 3.0f);
      int y0 = (int)gy; y0 = y0 > 2 ? 2 : y0;
      int x0 = (int)gx; x0 = x0 > 2 ? 2 : x0;
      const float fy = gy - (float)y0, fx = gx - (float)x0;
      u16* wp = (u16*)(smem + W_OFF) + m * 512 + p;   // elem [m][g][p] = m*512 + g*32 + p
      #pragma unroll
      for (int g = 0; g < 16; ++g) {
        const int y = g >> 2, x = g & 3;
        const float wyv = (y == y0) ? (1.0f - fy) : (y == y0 + 1) ? fy : 0.0f;
        const float wxv = (x == x0) ? (1.0f - fx) : (x == x0 + 1) ? fx : 0.0f;
        wp[g * 32] = rbf(win * wyv * wxv);
      }
    }
  }
  __syncthreads();

  f32x4 accA = {0.f, 0.f, 0.f, 0.f}, accB = {0.f, 0.f, 0.f, 0.f};

  // ================= h = 0: points 0..7 =================
  #pragma unroll
  for (int t = 0; t < 2; ++t) {
    const int mloc = wid * 2 + t;
    const int m = mloc;            // h=0
    const int* rp = recv + (n0 + m) * PP + l4 * 8;
    const int4 A4 = *(const int4*)rp;
    const int4 B4 = *(const int4*)(rp + 4);
    const short8 af = *(const short8*)(smem + W_OFF + m * 1024 + l15 * 64 + l4 * 16);
    u32 vo[8];
    vo[0] = (u32)A4.x * 64u + (u32)l15; vo[1] = (u32)A4.y * 64u + (u32)l15;
    vo[2] = (u32)A4.z * 64u + (u32)l15; vo[3] = (u32)A4.w * 64u + (u32)l15;
    vo[4] = (u32)B4.x * 64u + (u32)l15; vo[5] = (u32)B4.y * 64u + (u32)l15;
    vo[6] = (u32)B4.z * 64u + (u32)l15; vo[7] = (u32)B4.w * 64u + (u32)l15;
    f32x4 accm[4];
    #pragma unroll
    for (int ib = 0; ib < 4; ++ib) {
      u32 q[8];
      #pragma unroll
      for (int e = 0; e < 8; ++e) q[e] = (u32)fbf[vo[e] + ib * 16];
      union { u32 u[4]; short8 s; } bb;
      #pragma unroll
      for (int j = 0; j < 4; ++j) bb.u[j] = q[2 * j] | (q[2 * j + 1] << 16);
      const f32x4 cz = {0.f, 0.f, 0.f, 0.f};
      accm[ib] = __builtin_amdgcn_mfma_f32_16x16x32_bf16(af, bb.s, cz, 0, 0, 0);
    }
    #pragma unroll
    for (int ib = 0; ib < 4; ++ib)
      #pragma unroll
      for (int r = 0; r < 4; ++r) {
        const int g = l4 * 4 + r;
        const u32 k = (u32)(g * 64 + ib * 16 + l15);
        u32 byt = (u32)mloc * 2048u + k * 2u;
        byt ^= ((u32)((mloc & 7) ^ (g & 7)) << 4);
        *(u16*)(smem + MB_OFF + byt) = rbf(accm[ib][r]);
      }
  }
  __syncthreads();
  {
    const u32 rowb = (u32)(l15 & 7) * 2048u;
    const u32 swl = (u32)(l15 & 7) << 4;
    #pragma unroll 8
    for (int ks = 0; ks < 32; ++ks) {
      const u32 kc = (u32)ks * 32u + (u32)l4 * 8u;
      const u32 g7 = (((kc >> 6) & 7u) << 4);
      const u32 byt = (rowb + kc * 2u) ^ swl ^ g7;
      const short8 a2 = *(const short8*)(smem + MB_OFF + byt);
      const short8 b2 = *(const short8*)(k2f + ((u32)(ks * 4 + wid) * 64u + (u32)lane) * 8u);
      accA = __builtin_amdgcn_mfma_f32_16x16x32_bf16(a2, b2, accA, 0, 0, 0);
    }
  }
  __syncthreads();

  // ================= h = 1: points 8..15 =================
  #pragma unroll
  for (int t = 0; t < 2; ++t) {
    const int mloc = wid * 2 + t;
    const int m = 8 + mloc;        // h=1
    const int* rp = recv + (n0 + m) * PP + l4 * 8;
    const int4 A4 = *(const int4*)rp;
    const int4 B4 = *(const int4*)(rp + 4);
    const short8 af = *(const short8*)(smem + W_OFF + m * 1024 + l15 * 64 + l4 * 16);
    u32 vo[8];
    vo[0] = (u32)A4.x * 64u + (u32)l15; vo[1] = (u32)A4.y * 64u + (u32)l15;
    vo[2] = (u32)A4.z * 64u + (u32)l15; vo[3] = (u32)A4.w * 64u + (u32)l15;
    vo[4] = (u32)B4.x * 64u + (u32)l15; vo[5] = (u32)B4.y * 64u + (u32)l15;
    vo[6] = (u32)B4.z * 64u + (u32)l15; vo[7] = (u32)B4.w * 64u + (u32)l15;
    f32x4 accm[4];
    #pragma unroll
    for (int ib = 0; ib < 4; ++ib) {
      u32 q[8];
      #pragma unroll
      for (int e = 0; e < 8; ++e) q[e] = (u32)fbf[vo[e] + ib * 16];
      union { u32 u[4]; short8 s; } bb;
      #pragma unroll
      for (int j = 0; j < 4; ++j) bb.u[j] = q[2 * j] | (q[2 * j + 1] << 16);
      const f32x4 cz = {0.f, 0.f, 0.f, 0.f};
      accm[ib] = __builtin_amdgcn_mfma_f32_16x16x32_bf16(af, bb.s, cz, 0, 0, 0);
    }
    #pragma unroll
    for (int ib = 0; ib < 4; ++ib)
      #pragma unroll
      for (int r = 0; r < 4; ++r) {
        const int g = l4 * 4 + r;
        const u32 k = (u32)(g * 64 + ib * 16 + l15);
        u32 byt = (u32)mloc * 2048u + k * 2u;
        byt ^= ((u32)((mloc & 7) ^ (g & 7)) << 4);
        *(u16*)(smem + MB_OFF + byt) = rbf(accm[ib][r]);
      }
  }
  __syncthreads();
  {
    const u32 rowb = (u32)(l15 & 7) * 2048u;
    const u32 swl = (u32)(l15 & 7) << 4;
    #pragma unroll 8
    for (int ks = 0; ks < 32; ++ks) {
      const u32 kc = (u32)ks * 32u + (u32)l4 * 8u;
      const u32 g7 = (((kc >> 6) & 7u) << 4);
      const u32 byt = (rowb + kc * 2u) ^ swl ^ g7;
      const short8 a2 = *(const short8*)(smem + MB_OFF + byt);
      const short8 b2 = *(const short8*)(k2f + ((u32)(ks * 4 + wid) * 64u + (u32)lane) * 8u);
      accB = __builtin_amdgcn_mfma_f32_16x16x32_bf16(a2, b2, accB, 0, 0, 0);
    }
  }

  // ---- epilogue: rows n = l4*4 + r; l4<2 -> points 0-7 (accA), l4>=2 -> 8-15 (accB)
  const int o = wid * 16 + l15;
  const float bv = bias[o];
  const f32x4 accw = (l4 < 2) ? accA : accB;
  #pragma unroll
  for (int r = 0; r < 4; ++r)
    out[(n0 + l4 * 4 + r) * CH + o] = accw[r] * (1.0f / 32.0f) + bv;
}

extern "C" void kernel_launch(void* const* d_in, const int* in_sizes, int n_in,
                              void* d_out, int out_size, void* d_ws, size_t ws_size,
                              hipStream_t stream) {
  const float* features = (const float*)d_in[0];
  const int* receivers  = (const int*)d_in[1];
  const float* relpos   = (const float*)d_in[2];
  const float* wsup     = (const float*)d_in[3];
  const int* aptr       = (const int*)d_in[4];
  const float* kern     = (const float*)d_in[5];
  const float* bias     = (const float*)d_in[6];
  float* out = (float*)d_out;

  const int N = in_sizes[0] / CH;   // 50000
  u16* fbf = (u16*)d_ws;                                    // N*64 bf16 = 6.4 MB
  u16* k2f = (u16*)((char*)d_ws + (size_t)N * CH * 2);      // 128 KB, frag-ordered

  const int nfeat2 = in_sizes[0] / 2;
  prep_feat<<<dim3((nfeat2 + 255) / 256), dim3(256), 0, stream>>>(features, fbf, nfeat2);
  prep_k2f<<<dim3(65536 / 256), dim3(256), 0, stream>>>(kern, k2f);

  cconv_main<<<dim3(N / TM), dim3(THREADS), 0, stream>>>(
      receivers, relpos, wsup, aptr, fbf, k2f, bias, out);
}

// Round 7
// 55.392 us; speedup vs baseline: 2.5417x; 1.4719x over previous
//
#include <hip/hip_runtime.h>
#include <hip/hip_bf16.h>

typedef unsigned short u16;
typedef unsigned int u32;

#define THREADS 256
constexpr int CH = 64;        // in/out channels
constexpr int PP = 32;        // neighbors per point
constexpr int TM = 16;        // points per block

// ---- LDS layout (bytes) ----
// W:  [16 m][16 g][32 p] bf16, A-fragment order = 16384
// Mb: [16 pt][1024 k] bf16, XOR-swizzled (byte ^= ((m&7)^(g&7))<<4) = 32768
constexpr int W_OFF  = 0;
constexpr int MB_OFF = 16384;
constexpr int LDS_BYTES = 49152;   // 3 blocks/CU at 160 KiB

typedef __attribute__((ext_vector_type(8))) short short8;
typedef __attribute__((ext_vector_type(4))) float f32x4;

static __device__ __forceinline__ u16 f2bf_rne(float f) {
  __hip_bfloat16 h = __float2bfloat16(f);
  return __builtin_bit_cast(u16, h);
}
static __device__ __forceinline__ u16 rbf(float f) {  // cheap round-half-up (2 VALU)
  u32 u = __builtin_bit_cast(u32, f);
  return (u16)((u + 0x8000u) >> 16);
}

// ---- prep 1: features f32 -> bf16 ----
__global__ void prep_feat(const float* __restrict__ in, u16* __restrict__ outb, int n2) {
  int i = blockIdx.x * blockDim.x + threadIdx.x;
  if (i < n2) {
    float2 v = ((const float2*)in)[i];
    u32 u = (u32)f2bf_rne(v.x) | ((u32)f2bf_rne(v.y) << 16);
    ((u32*)outb)[i] = u;
  }
}

// ---- prep 2: kernel f32 [g][i][o] -> bf16 in B-fragment order ----
__global__ void prep_k2f(const float* __restrict__ kern, u16* __restrict__ k2f) {
  int d = blockIdx.x * blockDim.x + threadIdx.x;   // 65536 total
  int e = d & 7, l = (d >> 3) & 63, ot = (d >> 9) & 3, ks = d >> 11;
  int k = ks * 32 + (l >> 4) * 8 + e;
  int o = ot * 16 + (l & 15);
  k2f[d] = f2bf_rne(kern[k * 64 + o]);
}

// ---- main fused kernel: 16 points per block, 4 waves, 3 blocks/CU ----
__global__ __launch_bounds__(THREADS, 3) void cconv_main(
    const int* __restrict__ recv, const float* __restrict__ relpos,
    const float* __restrict__ wsup, const int* __restrict__ aptr,
    const u16* __restrict__ fbf, const u16* __restrict__ k2f,
    const float* __restrict__ bias, float* __restrict__ out) {
  __shared__ __align__(16) char smem[LDS_BYTES];
  const int tid = threadIdx.x;
  const int n0 = blockIdx.x * TM;
  const int wid = tid >> 6, lane = tid & 63;
  const int l15 = lane & 15, l4 = lane >> 4;

  // ---- P0: full W -> LDS in A-fragment order [m][g][p] ----
  {
    const float invws = 1.0f / wsup[0];
    int a = aptr[0];
    if (a < 0 || a > 64) a = (int)(*(const float*)aptr);  // dtype fallback
    #pragma unroll
    for (int ee = 0; ee < 2; ++ee) {
      const int e = tid + ee * 256;
      const int m = e >> 5, p = e & 31;
      const int ei = (n0 + m) * PP + p;
      const float2 rp2 = ((const float2*)relpos)[ei];
      const float rx = rp2.x * invws, ry = rp2.y * invws;
      const float d2 = rx * rx + ry * ry;
      const float w1 = fmaxf(1.0f - d2, 0.0f);
      float win = 1.0f;
      for (int q = 0; q < a; ++q) win *= w1;
      float gy = fminf(fmaxf((rx + 1.0f) * 1.5f, 0.0f), 3.0f);
      float gx = fminf(fmaxf((ry + 1.0f) * 1.5f, 0.0f), 3.0f);
      int y0 = (int)gy; y0 = y0 > 2 ? 2 : y0;
      int x0 = (int)gx; x0 = x0 > 2 ? 2 : x0;
      const float fy = gy - (float)y0, fx = gx - (float)x0;
      u16* wp = (u16*)(smem + W_OFF) + m * 512 + p;   // elem [m][g][p] = m*512 + g*32 + p
      #pragma unroll
      for (int g = 0; g < 16; ++g) {
        const int y = g >> 2, x = g & 3;
        const float wyv = (y == y0) ? (1.0f - fy) : (y == y0 + 1) ? fy : 0.0f;
        const float wxv = (x == x0) ? (1.0f - fx) : (x == x0 + 1) ? fx : 0.0f;
        wp[g * 32] = rbf(win * wyv * wxv);
      }
    }
  }
  __syncthreads();

  // ---- build phase: each wave builds 4 points into Mb[16 pts] ----
  #pragma unroll
  for (int t = 0; t < 4; ++t) {
    const int m = wid * 4 + t;     // point 0..15, distinct per (wid,t)
    const int* rp = recv + (n0 + m) * PP + l4 * 8;
    const int4 A4 = *(const int4*)rp;
    const int4 B4 = *(const int4*)(rp + 4);
    const short8 af = *(const short8*)(smem + W_OFF + m * 1024 + l15 * 64 + l4 * 16);
    u32 vo[8];
    vo[0] = (u32)A4.x * 64u + (u32)l15; vo[1] = (u32)A4.y * 64u + (u32)l15;
    vo[2] = (u32)A4.z * 64u + (u32)l15; vo[3] = (u32)A4.w * 64u + (u32)l15;
    vo[4] = (u32)B4.x * 64u + (u32)l15; vo[5] = (u32)B4.y * 64u + (u32)l15;
    vo[6] = (u32)B4.z * 64u + (u32)l15; vo[7] = (u32)B4.w * 64u + (u32)l15;
    f32x4 accm[4];
    #pragma unroll
    for (int ib = 0; ib < 4; ++ib) {
      u32 q[8];
      #pragma unroll
      for (int e = 0; e < 8; ++e) q[e] = (u32)fbf[vo[e] + ib * 16];
      union { u32 u[4]; short8 s; } bb;
      #pragma unroll
      for (int j = 0; j < 4; ++j) bb.u[j] = q[2 * j] | (q[2 * j + 1] << 16);
      const f32x4 cz = {0.f, 0.f, 0.f, 0.f};
      accm[ib] = __builtin_amdgcn_mfma_f32_16x16x32_bf16(af, bb.s, cz, 0, 0, 0);
    }
    #pragma unroll
    for (int ib = 0; ib < 4; ++ib)
      #pragma unroll
      for (int r = 0; r < 4; ++r) {
        const int g = l4 * 4 + r;
        const u32 k = (u32)(g * 64 + ib * 16 + l15);
        u32 byt = (u32)m * 2048u + k * 2u;
        byt ^= ((u32)((m & 7) ^ (g & 7)) << 4);
        *(u16*)(smem + MB_OFF + byt) = rbf(accm[ib][r]);
      }
  }
  __syncthreads();

  // ---- single GEMM2: acc[16n x 16o per wave] = Mb[16n x 1024k] @ K2[1024k x 64o] ----
  f32x4 acc = {0.f, 0.f, 0.f, 0.f};
  {
    const u32 rowb = (u32)l15 * 2048u;
    const u32 swl = (u32)(l15 & 7) << 4;
    #pragma unroll 8
    for (int ks = 0; ks < 32; ++ks) {
      const u32 kc = (u32)ks * 32u + (u32)l4 * 8u;
      const u32 g7 = (((kc >> 6) & 7u) << 4);
      const u32 byt = (rowb + kc * 2u) ^ swl ^ g7;
      const short8 a2 = *(const short8*)(smem + MB_OFF + byt);
      const short8 b2 = *(const short8*)(k2f + ((u32)(ks * 4 + wid) * 64u + (u32)lane) * 8u);
      acc = __builtin_amdgcn_mfma_f32_16x16x32_bf16(a2, b2, acc, 0, 0, 0);
    }
  }

  // ---- epilogue: rows n = l4*4 + r (points), col o = wid*16 + l15 ----
  const int o = wid * 16 + l15;
  const float bv = bias[o];
  #pragma unroll
  for (int r = 0; r < 4; ++r)
    out[(n0 + l4 * 4 + r) * CH + o] = acc[r] * (1.0f / 32.0f) + bv;
}

extern "C" void kernel_launch(void* const* d_in, const int* in_sizes, int n_in,
                              void* d_out, int out_size, void* d_ws, size_t ws_size,
                              hipStream_t stream) {
  const float* features = (const float*)d_in[0];
  const int* receivers  = (const int*)d_in[1];
  const float* relpos   = (const float*)d_in[2];
  const float* wsup     = (const float*)d_in[3];
  const int* aptr       = (const int*)d_in[4];
  const float* kern     = (const float*)d_in[5];
  const float* bias     = (const float*)d_in[6];
  float* out = (float*)d_out;

  const int N = in_sizes[0] / CH;   // 50000
  u16* fbf = (u16*)d_ws;                                    // N*64 bf16 = 6.4 MB
  u16* k2f = (u16*)((char*)d_ws + (size_t)N * CH * 2);      // 128 KB, frag-ordered

  const int nfeat2 = in_sizes[0] / 2;
  prep_feat<<<dim3((nfeat2 + 255) / 256), dim3(256), 0, stream>>>(features, fbf, nfeat2);
  prep_k2f<<<dim3(65536 / 256), dim3(256), 0, stream>>>(kern, k2f);

  cconv_main<<<dim3(N / TM), dim3(THREADS), 0, stream>>>(
      receivers, relpos, wsup, aptr, fbf, k2f, bias, out);
}

// Round 8
// 54.947 us; speedup vs baseline: 2.5623x; 1.0081x over previous
//
#include <hip/hip_runtime.h>
#include <hip/hip_bf16.h>

typedef unsigned short u16;
typedef unsigned int u32;

#define THREADS 256
constexpr int CH = 64;        // in/out channels
constexpr int PP = 32;        // neighbors per point
constexpr int TM = 16;        // points per block

// ---- LDS layout (bytes) ----
// W:  [16 m][16 g][32 p] bf16, A-fragment order = 16384
// Mb: [16 pt][1024 k] bf16, XOR-swizzled (byte ^= ((m&7)^(g&7))<<4) = 32768
constexpr int W_OFF  = 0;
constexpr int MB_OFF = 16384;
constexpr int LDS_BYTES = 49152;   // 3 blocks/CU at 160 KiB

typedef __attribute__((ext_vector_type(8))) short short8;
typedef __attribute__((ext_vector_type(4))) float f32x4;

static __device__ __forceinline__ u16 f2bf_rne(float f) {
  __hip_bfloat16 h = __float2bfloat16(f);
  return __builtin_bit_cast(u16, h);
}
static __device__ __forceinline__ u16 rbf(float f) {  // cheap round-half-up (2 VALU)
  u32 u = __builtin_bit_cast(u32, f);
  return (u16)((u + 0x8000u) >> 16);
}

// ---- prep 1: features f32 -> bf16 ----
__global__ void prep_feat(const float* __restrict__ in, u16* __restrict__ outb, int n2) {
  int i = blockIdx.x * blockDim.x + threadIdx.x;
  if (i < n2) {
    float2 v = ((const float2*)in)[i];
    u32 u = (u32)f2bf_rne(v.x) | ((u32)f2bf_rne(v.y) << 16);
    ((u32*)outb)[i] = u;
  }
}

// ---- prep 2: kernel f32 [g][i][o] -> bf16 in B-fragment order ----
__global__ void prep_k2f(const float* __restrict__ kern, u16* __restrict__ k2f) {
  int d = blockIdx.x * blockDim.x + threadIdx.x;   // 65536 total
  int e = d & 7, l = (d >> 3) & 63, ot = (d >> 9) & 3, ks = d >> 11;
  int k = ks * 32 + (l >> 4) * 8 + e;
  int o = ot * 16 + (l & 15);
  k2f[d] = f2bf_rne(kern[k * 64 + o]);
}

// issue the 32 feature loads for one point (8 neighbors x 4 ib-blocks)
#define LOADQ(qv, A4_, B4_) do {                                                \
    u32 vo[8];                                                                  \
    vo[0] = (u32)(A4_).x * 64u + (u32)l15; vo[1] = (u32)(A4_).y * 64u + (u32)l15; \
    vo[2] = (u32)(A4_).z * 64u + (u32)l15; vo[3] = (u32)(A4_).w * 64u + (u32)l15; \
    vo[4] = (u32)(B4_).x * 64u + (u32)l15; vo[5] = (u32)(B4_).y * 64u + (u32)l15; \
    vo[6] = (u32)(B4_).z * 64u + (u32)l15; vo[7] = (u32)(B4_).w * 64u + (u32)l15; \
    _Pragma("unroll")                                                           \
    for (int ib = 0; ib < 4; ++ib)                                              \
      _Pragma("unroll")                                                         \
      for (int e = 0; e < 8; ++e) qv[ib * 8 + e] = (u32)fbf[vo[e] + ib * 16];   \
  } while (0)

// consume one point's loads: pack -> 4 MFMA -> stage into swizzled Mb
#define COMPUTE(t_, qv) do {                                                    \
    const int m_c = wid * 4 + (t_);                                             \
    const short8 af = *(const short8*)(smem + W_OFF + m_c * 1024 + l15 * 64 + l4 * 16); \
    f32x4 accm[4];                                                              \
    _Pragma("unroll")                                                           \
    for (int ib = 0; ib < 4; ++ib) {                                            \
      union { u32 u[4]; short8 s; } bb;                                         \
      _Pragma("unroll")                                                         \
      for (int j = 0; j < 4; ++j)                                               \
        bb.u[j] = qv[ib * 8 + 2 * j] | (qv[ib * 8 + 2 * j + 1] << 16);          \
      const f32x4 cz = {0.f, 0.f, 0.f, 0.f};                                    \
      accm[ib] = __builtin_amdgcn_mfma_f32_16x16x32_bf16(af, bb.s, cz, 0, 0, 0);\
    }                                                                           \
    _Pragma("unroll")                                                           \
    for (int ib = 0; ib < 4; ++ib)                                              \
      _Pragma("unroll")                                                         \
      for (int r = 0; r < 4; ++r) {                                             \
        const int g = l4 * 4 + r;                                               \
        const u32 k = (u32)(g * 64 + ib * 16 + l15);                            \
        u32 byt = (u32)m_c * 2048u + k * 2u;                                    \
        byt ^= ((u32)((m_c & 7) ^ (g & 7)) << 4);                               \
        *(u16*)(smem + MB_OFF + byt) = rbf(accm[ib][r]);                        \
      }                                                                         \
  } while (0)

// ---- main fused kernel: 16 points per block, 4 waves, 3 blocks/CU ----
__global__ __launch_bounds__(THREADS, 3) void cconv_main(
    const int* __restrict__ recv, const float* __restrict__ relpos,
    const float* __restrict__ wsup, const int* __restrict__ aptr,
    const u16* __restrict__ fbf, const u16* __restrict__ k2f,
    const float* __restrict__ bias, float* __restrict__ out) {
  __shared__ __align__(16) char smem[LDS_BYTES];
  const int tid = threadIdx.x;
  const int n0 = blockIdx.x * TM;
  const int wid = tid >> 6, lane = tid & 63;
  const int l15 = lane & 15, l4 = lane >> 4;

  // ---- hoist this wave's 8 receiver int4 loads: latency hides under P0 ----
  const int* rbase = recv + (n0 + wid * 4) * PP + l4 * 8;
  const int4 A40 = *(const int4*)(rbase + 0 * PP);
  const int4 B40 = *(const int4*)(rbase + 0 * PP + 4);
  const int4 A41 = *(const int4*)(rbase + 1 * PP);
  const int4 B41 = *(const int4*)(rbase + 1 * PP + 4);
  const int4 A42 = *(const int4*)(rbase + 2 * PP);
  const int4 B42 = *(const int4*)(rbase + 2 * PP + 4);
  const int4 A43 = *(const int4*)(rbase + 3 * PP);
  const int4 B43 = *(const int4*)(rbase + 3 * PP + 4);

  // ---- P0: full W -> LDS in A-fragment order [m][g][p] ----
  {
    const float invws = 1.0f / wsup[0];
    int a = aptr[0];
    if (a < 0 || a > 64) a = (int)(*(const float*)aptr);  // dtype fallback
    #pragma unroll
    for (int ee = 0; ee < 2; ++ee) {
      const int e = tid + ee * 256;
      const int m = e >> 5, p = e & 31;
      const int ei = (n0 + m) * PP + p;
      const float2 rp2 = ((const float2*)relpos)[ei];
      const float rx = rp2.x * invws, ry = rp2.y * invws;
      const float d2 = rx * rx + ry * ry;
      const float w1 = fmaxf(1.0f - d2, 0.0f);
      float win = 1.0f;
      for (int q = 0; q < a; ++q) win *= w1;
      float gy = fminf(fmaxf((rx + 1.0f) * 1.5f, 0.0f), 3.0f);
      float gx = fminf(fmaxf((ry + 1.0f) * 1.5f, 0.0f), 3.0f);
      int y0 = (int)gy; y0 = y0 > 2 ? 2 : y0;
      int x0 = (int)gx; x0 = x0 > 2 ? 2 : x0;
      const float fy = gy - (float)y0, fx = gx - (float)x0;
      u16* wp = (u16*)(smem + W_OFF) + m * 512 + p;   // elem [m][g][p] = m*512 + g*32 + p
      #pragma unroll
      for (int g = 0; g < 16; ++g) {
        const int y = g >> 2, x = g & 3;
        const float wyv = (y == y0) ? (1.0f - fy) : (y == y0 + 1) ? fy : 0.0f;
        const float wxv = (x == x0) ? (1.0f - fx) : (x == x0 + 1) ? fx : 0.0f;
        wp[g * 32] = rbf(win * wyv * wxv);
      }
    }
  }
  __syncthreads();

  // ---- build phase: 4 points per wave, 2-deep load/compute pipeline ----
  {
    u32 q0[32], q1[32], q2[32], q3[32];
    LOADQ(q0, A40, B40);
    LOADQ(q1, A41, B41);
    COMPUTE(0, q0);
    LOADQ(q2, A42, B42);
    COMPUTE(1, q1);
    LOADQ(q3, A43, B43);
    COMPUTE(2, q2);
    COMPUTE(3, q3);
  }
  __syncthreads();

  // ---- single GEMM2: acc[16n x 16o per wave] = Mb[16n x 1024k] @ K2[1024k x 64o] ----
  f32x4 acc = {0.f, 0.f, 0.f, 0.f};
  {
    const u32 rowb = (u32)l15 * 2048u;
    const u32 swl = (u32)(l15 & 7) << 4;
    #pragma unroll 8
    for (int ks = 0; ks < 32; ++ks) {
      const u32 kc = (u32)ks * 32u + (u32)l4 * 8u;
      const u32 g7 = (((kc >> 6) & 7u) << 4);
      const u32 byt = (rowb + kc * 2u) ^ swl ^ g7;
      const short8 a2 = *(const short8*)(smem + MB_OFF + byt);
      const short8 b2 = *(const short8*)(k2f + ((u32)(ks * 4 + wid) * 64u + (u32)lane) * 8u);
      acc = __builtin_amdgcn_mfma_f32_16x16x32_bf16(a2, b2, acc, 0, 0, 0);
    }
  }

  // ---- epilogue: rows n = l4*4 + r (points), col o = wid*16 + l15 ----
  const int o = wid * 16 + l15;
  const float bv = bias[o];
  #pragma unroll
  for (int r = 0; r < 4; ++r)
    out[(n0 + l4 * 4 + r) * CH + o] = acc[r] * (1.0f / 32.0f) + bv;
}

extern "C" void kernel_launch(void* const* d_in, const int* in_sizes, int n_in,
                              void* d_out, int out_size, void* d_ws, size_t ws_size,
                              hipStream_t stream) {
  const float* features = (const float*)d_in[0];
  const int* receivers  = (const int*)d_in[1];
  const float* relpos   = (const float*)d_in[2];
  const float* wsup     = (const float*)d_in[3];
  const int* aptr       = (const int*)d_in[4];
  const float* kern     = (const float*)d_in[5];
  const float* bias     = (const float*)d_in[6];
  float* out = (float*)d_out;

  const int N = in_sizes[0] / CH;   // 50000
  u16* fbf = (u16*)d_ws;                                    // N*64 bf16 = 6.4 MB
  u16* k2f = (u16*)((char*)d_ws + (size_t)N * CH * 2);      // 128 KB, frag-ordered

  const int nfeat2 = in_sizes[0] / 2;
  prep_feat<<<dim3((nfeat2 + 255) / 256), dim3(256), 0, stream>>>(features, fbf, nfeat2);
  prep_k2f<<<dim3(65536 / 256), dim3(256), 0, stream>>>(kern, k2f);

  cconv_main<<<dim3(N / TM), dim3(THREADS), 0, stream>>>(
      receivers, relpos, wsup, aptr, fbf, k2f, bias, out);
}